// Round 8
// baseline (5463.969 us; speedup 1.0000x reference)
//
#include <hip/hip_runtime.h>

typedef unsigned short u16;
typedef unsigned int u32;
typedef unsigned long long u64;
using f32x4 = __attribute__((ext_vector_type(4))) float;
using s16x8 = __attribute__((ext_vector_type(8))) short;
using u32x4 = __attribute__((ext_vector_type(4))) unsigned int;

constexpr int Tn = 512, Bn = 64, Hn = 512, Gn = 2048, On = 128;
constexpr int NS = 16;  // gate-slice WGs per batch group
constexpr int NG = 4;   // batch groups (independent)

// -------- workspace layout (bytes) --------
constexpr size_t OFF_CMID = 0;                                   // [B][H] f32 = 128 KB
constexpr size_t OFF_HMID = OFF_CMID + (size_t)Bn * Hn * 4;      // [B][H] f32 = 128 KB
constexpr size_t OFF_WB   = OFF_HMID + (size_t)Bn * Hn * 4;      // [G][H] bf16 = 2 MB (shared W_ih buffer)
constexpr size_t OFF_HT   = OFF_WB + (size_t)Gn * Hn * 2;        // [T+1][B][H] bf16 = 33.6 MB (trail; also x_bf before scan1)
constexpr size_t OFF_XG   = OFF_HT + (size_t)(Tn + 1) * Bn * Hn * 2;  // [T][G][B] bf16 = 128 MB

// -------- helpers --------
__device__ __forceinline__ u16 f2b(float f) {
  union { float f; unsigned u; } v; v.f = f;
  unsigned r = v.u + 0x7fffu + ((v.u >> 16) & 1u);
  return (u16)(r >> 16);
}
__device__ __forceinline__ float b2f(u16 u) {
  union { unsigned u; float f; } v; v.u = ((unsigned)u) << 16; return v.f;
}
__device__ __forceinline__ s16x8 pack8(float4 lo, float4 hi) {
  s16x8 r;
  r[0] = (short)f2b(lo.x); r[1] = (short)f2b(lo.y); r[2] = (short)f2b(lo.z); r[3] = (short)f2b(lo.w);
  r[4] = (short)f2b(hi.x); r[5] = (short)f2b(hi.y); r[6] = (short)f2b(hi.z); r[7] = (short)f2b(hi.w);
  return r;
}
__device__ __forceinline__ float sigm(float x) {
  float e = __builtin_amdgcn_exp2f(-1.4426950408889634f * x);
  return __builtin_amdgcn_rcpf(1.0f + e);
}
__device__ __forceinline__ float tanh_(float x) {
  float e = __builtin_amdgcn_exp2f(-2.885390081777927f * x);
  return __builtin_amdgcn_rcpf(1.0f + e) * 2.0f - 1.0f;
}
// agent-scope (device-coherent, IC-visible) relaxed atomics — proven exchange path
__device__ __forceinline__ void st64_sc(u64* p, u64 v) {
  __hip_atomic_store(p, v, __ATOMIC_RELAXED, __HIP_MEMORY_SCOPE_AGENT);
}

// -------- f32 -> bf16 bulk convert --------
__global__ __launch_bounds__(256)
void cvt_kernel(const float* __restrict__ in, u16* __restrict__ out, int n4) {
  const int i = blockIdx.x * 256 + threadIdx.x;
  if (i < n4) {
    float4 v = ((const float4*)in)[i];
    ushort4 o; o.x = f2b(v.x); o.y = f2b(v.y); o.z = f2b(v.z); o.w = f2b(v.w);
    ((ushort4*)out)[i] = o;
  }
}

// -------- projection GEMM (all-bf16): xg[t][n][b] = A[m][:] . W[n][:] + bih[n] + bhh[n] --------
__global__ __launch_bounds__(256)
void proj_kernel(const u16* __restrict__ Ap, const u16* __restrict__ Wb,
                 const float* __restrict__ bih, const float* __restrict__ bhh,
                 u16* __restrict__ xg)
{
  const int lane = threadIdx.x & 63, wave = threadIdx.x >> 6;
  const int lrow = lane & 15, lk8 = (lane >> 4) << 3;
  const int m0 = blockIdx.y * 128 + (wave & 1) * 64;
  const int n0 = blockIdx.x * 128 + (wave >> 1) * 64;
  f32x4 acc[4][4] = {};
  for (int ks = 0; ks < 16; ++ks) {
    const int k0 = ks * 32 + lk8;
    s16x8 af[4], bfr[4];
#pragma unroll
    for (int mt = 0; mt < 4; ++mt)
      af[mt] = *(const s16x8*)(Ap + (size_t)(m0 + mt * 16 + lrow) * Hn + k0);
#pragma unroll
    for (int nt = 0; nt < 4; ++nt)
      bfr[nt] = *(const s16x8*)(Wb + (size_t)(n0 + nt * 16 + lrow) * Hn + k0);
#pragma unroll
    for (int mt = 0; mt < 4; ++mt)
#pragma unroll
      for (int nt = 0; nt < 4; ++nt)
        acc[mt][nt] = __builtin_amdgcn_mfma_f32_16x16x32_bf16(af[mt], bfr[nt], acc[mt][nt], 0, 0, 0);
  }
  const int rbase = (lane >> 4) << 2;
#pragma unroll
  for (int nt = 0; nt < 4; ++nt) {
    const int n = n0 + nt * 16 + lrow;
    const float bias = bih[n] + bhh[n];
#pragma unroll
    for (int mt = 0; mt < 4; ++mt) {
      const int m = m0 + mt * 16 + rbase;
      const int t = m >> 6, b = m & 63;
      ushort4 v;
      v.x = f2b(acc[mt][nt][0] + bias);
      v.y = f2b(acc[mt][nt][1] + bias);
      v.z = f2b(acc[mt][nt][2] + bias);
      v.w = f2b(acc[mt][nt][3] + bias);
      *(ushort4*)(xg + ((size_t)t * Gn + n) * Bn + b) = v;
    }
  }
}

// 16 fragment-layout poll loads (sc1 = agent-coherent), issued without waits
#define POLL16(PB)                                                                              \
  asm volatile("global_load_dwordx4 %0, %1, off sc1"            : "=v"(afr[0])  : "v"(PB) : "memory"); \
  asm volatile("global_load_dwordx4 %0, %1, off offset:64 sc1"  : "=v"(afr[1])  : "v"(PB) : "memory"); \
  asm volatile("global_load_dwordx4 %0, %1, off offset:128 sc1" : "=v"(afr[2])  : "v"(PB) : "memory"); \
  asm volatile("global_load_dwordx4 %0, %1, off offset:192 sc1" : "=v"(afr[3])  : "v"(PB) : "memory"); \
  asm volatile("global_load_dwordx4 %0, %1, off offset:256 sc1" : "=v"(afr[4])  : "v"(PB) : "memory"); \
  asm volatile("global_load_dwordx4 %0, %1, off offset:320 sc1" : "=v"(afr[5])  : "v"(PB) : "memory"); \
  asm volatile("global_load_dwordx4 %0, %1, off offset:384 sc1" : "=v"(afr[6])  : "v"(PB) : "memory"); \
  asm volatile("global_load_dwordx4 %0, %1, off offset:448 sc1" : "=v"(afr[7])  : "v"(PB) : "memory"); \
  asm volatile("global_load_dwordx4 %0, %1, off offset:512 sc1" : "=v"(afr[8])  : "v"(PB) : "memory"); \
  asm volatile("global_load_dwordx4 %0, %1, off offset:576 sc1" : "=v"(afr[9])  : "v"(PB) : "memory"); \
  asm volatile("global_load_dwordx4 %0, %1, off offset:640 sc1" : "=v"(afr[10]) : "v"(PB) : "memory"); \
  asm volatile("global_load_dwordx4 %0, %1, off offset:704 sc1" : "=v"(afr[11]) : "v"(PB) : "memory"); \
  asm volatile("global_load_dwordx4 %0, %1, off offset:768 sc1" : "=v"(afr[12]) : "v"(PB) : "memory"); \
  asm volatile("global_load_dwordx4 %0, %1, off offset:832 sc1" : "=v"(afr[13]) : "v"(PB) : "memory"); \
  asm volatile("global_load_dwordx4 %0, %1, off offset:896 sc1" : "=v"(afr[14]) : "v"(PB) : "memory"); \
  asm volatile("global_load_dwordx4 %0, %1, off offset:960 sc1" : "=v"(afr[15]) : "v"(PB) : "memory");

// -------- persistent LSTM scan: direct-fragment poll, 1 barrier/step, no LDS h-tile --------
// ht: [T+1][B][H] bf16, pre-poisoned 0xFF. Region t = h after step t-1; region 0 = h0.
// WG (g,s): batch rows g*16..+16, gate-cols s*32..+32. Poll loads ARE the MFMA A-fragments.
__global__ __launch_bounds__(256, 1)
void scan_kernel(const u16* __restrict__ xg, const float* __restrict__ Whh,
                 const float* __restrict__ hinit, const float* __restrict__ cinit,
                 u16* __restrict__ ht, float* __restrict__ h_fin, float* __restrict__ c_fin)
{
  const int g = blockIdx.x >> 4, s = blockIdx.x & (NS - 1);
  const int tid = threadIdx.x;
  const int lane = tid & 63, w = tid >> 6;
  const int x16 = lane & 15, grp = lane >> 4;
  const int jj = x16 & 7;
  const int j0 = s * 32 + w * 8;
  const int brow = g * 16;
  const int bth = brow + grp * 4;

  __shared__ u16 hstage[16][32];   // WG's h-slice staging for coalesced publish

  // loop-invariant weight fragments (32 gate-rows x K=512 per wave, one-time pack)
  s16x8 bw[2][16];
#pragma unroll
  for (int nt = 0; nt < 2; ++nt) {
    const int q = nt * 2 + (x16 >> 3);                    // gate 0..3 (i,f,g,o)
    const size_t grow = (size_t)q * Hn + j0 + jj;
#pragma unroll
    for (int ks = 0; ks < 16; ++ks) {
      const float* wp = Whh + grow * Hn + ks * 32 + grp * 8;
      float4 lo = *(const float4*)wp, hi = *(const float4*)(wp + 4);
      bw[nt][ks] = pack8(lo, hi);
    }
  }

  float c[4];
#pragma unroll
  for (int r = 0; r < 4; ++r) c[r] = cinit[(size_t)(bth + r) * Hn + j0 + jj];

  // publish region 0 slice from hinit (f32 -> bf16)
  if (tid < 128) {
    const int row = tid >> 3, cq = tid & 7;
    const float* hp = hinit + (size_t)(brow + row) * Hn + s * 32 + cq * 4;
    u64 v = (u64)f2b(hp[0]) | ((u64)f2b(hp[1]) << 16)
          | ((u64)f2b(hp[2]) << 32) | ((u64)f2b(hp[3]) << 48);
    st64_sc((u64*)(ht + (size_t)(brow + row) * Hn + s * 32 + cq * 4), v);
  }

  const size_t grow0 = (size_t)(0 * 2 + (x16 >> 3)) * Hn + j0 + jj;
  const size_t grow1 = (size_t)(1 * 2 + (x16 >> 3)) * Hn + j0 + jj;
  ushort4 xv0 = *(const ushort4*)(xg + grow0 * Bn + bth);
  ushort4 xv1 = *(const ushort4*)(xg + grow1 * Bn + bth);

  for (int t = 0; t < Tn; ++t) {
    const u16* rt = ht + (size_t)t * Bn * Hn;
    // fragment base: row (brow+x16), k-offset grp*8 -> chunk ks at +ks*64 bytes.
    // Chunk ks lies entirely in producer s'=ks's published 8B units.
    const char* pb = (const char*)rt + ((size_t)(brow + x16) * Hn + (size_t)grp * 8) * 2;
    u32x4 afr[16];
    POLL16(pb);
    // xg prefetch for t+1 issued AFTER the polls, BEFORE the wait: vmcnt(2) drains
    // exactly the 16 polls (in-order retirement), xg stays in flight and completes
    // ~1.3us before the publish barrier. Clamped index keeps the count at exactly 2.
    const int tn = (t + 1 < Tn) ? t + 1 : t;
    ushort4 xn0 = *(const ushort4*)(xg + ((size_t)tn * Gn + grow0) * Bn + bth);
    ushort4 xn1 = *(const ushort4*)(xg + ((size_t)tn * Gn + grow1) * Bn + bth);
    asm volatile("s_waitcnt vmcnt(2)" ::: "memory");
    // poison check per 8B store unit: valid bf16 h != 0xFFFF, so u32 pair half == ~0 <=> poison
    while (true) {
      bool bad = false;
#pragma unroll
      for (int i = 0; i < 16; ++i) bad = bad | (afr[i][0] == ~0u) | (afr[i][2] == ~0u);
      if (!bad) break;
      POLL16(pb);
      asm volatile("s_waitcnt vmcnt(0)" ::: "memory");
    }

    f32x4 acc0, acc1;
    acc0[0] = b2f(xv0.x); acc0[1] = b2f(xv0.y); acc0[2] = b2f(xv0.z); acc0[3] = b2f(xv0.w);
    acc1[0] = b2f(xv1.x); acc1[1] = b2f(xv1.y); acc1[2] = b2f(xv1.z); acc1[3] = b2f(xv1.w);
#pragma unroll
    for (int ks = 0; ks < 16; ++ks) {
      const s16x8 a = *(const s16x8*)&afr[ks];
      acc0 = __builtin_amdgcn_mfma_f32_16x16x32_bf16(a, bw[0][ks], acc0, 0, 0, 0);
      acc1 = __builtin_amdgcn_mfma_f32_16x16x32_bf16(a, bw[1][ks], acc1, 0, 0, 0);
    }
    // tile0 rows: i(j)/f(j); tile1: g(j)/o(j); pair via shfl_xor(8)
    float hv[4];
#pragma unroll
    for (int r = 0; r < 4; ++r) {
      const float p0v = acc0[r], p1v = acc1[r];
      const float q0 = __shfl_xor(p0v, 8, 64);
      const float q1 = __shfl_xor(p1v, 8, 64);
      const bool lo = (x16 < 8);
      const float gi = lo ? p0v : q0;
      const float gf = lo ? q0 : p0v;
      const float gg = lo ? p1v : q1;
      const float go = lo ? q1 : p1v;
      const float cn = sigm(gf) * c[r] + sigm(gi) * tanh_(gg);
      c[r] = cn;
      hv[r] = sigm(go) * tanh_(cn);
    }
    if (x16 < 8) {
#pragma unroll
      for (int r = 0; r < 4; ++r) {
        hstage[grp * 4 + r][w * 8 + jj] = f2b(hv[r]);
        if (t == Tn - 1) {
          h_fin[(size_t)(bth + r) * Hn + j0 + jj] = hv[r];
          c_fin[(size_t)(bth + r) * Hn + j0 + jj] = c[r];
        }
      }
    }
    xv0 = xn0; xv1 = xn1;
    __syncthreads();   // the ONLY barrier: hstage complete before publishers read it.
    // WAR on hstage is safe: next write happens after poll(t+1) success, which implies
    // self-WG's publishers (spanning all 4 waves) completed their hstage reads.
    if (!(tid & 1)) {
      const int q = tid >> 1, row = q >> 3, cq = q & 7;
      const u64 yv = *(const u64*)&hstage[row][cq * 4];
      st64_sc((u64*)(ht + (size_t)(t + 1) * Bn * Hn + (size_t)(brow + row) * Hn + s * 32 + cq * 4), yv);
    }
  }
}

// -------- output head --------
__global__ __launch_bounds__(128)
void out_kernel(const float* __restrict__ h2, const float* __restrict__ Wout,
                const float* __restrict__ bout, float* __restrict__ out)
{
  const int b = blockIdx.x, o = threadIdx.x;
  const float4* hp = (const float4*)(h2 + (size_t)b * Hn);
  const float4* wp = (const float4*)(Wout + (size_t)o * Hn);
  float acc = 0.f;
#pragma unroll 4
  for (int k = 0; k < Hn / 4; ++k) {
    float4 h4 = hp[k], w4 = wp[k];
    acc += h4.x * w4.x + h4.y * w4.y + h4.z * w4.z + h4.w * w4.w;
  }
  out[(size_t)b * On + o] = acc + bout[o];
}

extern "C" void kernel_launch(void* const* d_in, const int* in_sizes, int n_in,
                              void* d_out, int out_size, void* d_ws, size_t ws_size,
                              hipStream_t stream) {
  const float* x     = (const float*)d_in[0];
  const float* h0    = (const float*)d_in[1];
  const float* c0    = (const float*)d_in[2];
  const float* W_ih1 = (const float*)d_in[3];
  const float* W_hh1 = (const float*)d_in[4];
  const float* b_ih1 = (const float*)d_in[5];
  const float* b_hh1 = (const float*)d_in[6];
  const float* W_ih2 = (const float*)d_in[7];
  const float* W_hh2 = (const float*)d_in[8];
  const float* b_ih2 = (const float*)d_in[9];
  const float* b_hh2 = (const float*)d_in[10];
  const float* W_out = (const float*)d_in[11];
  const float* b_out = (const float*)d_in[12];

  float* out    = (float*)d_out;
  float* h2_out = out + (size_t)Bn * On;
  float* c2_out = h2_out + (size_t)Bn * Hn;

  char* w = (char*)d_ws;
  float* c_mid = (float*)(w + OFF_CMID);
  float* h_mid = (float*)(w + OFF_HMID);
  u16*   Wb    = (u16*)(w + OFF_WB);
  u16*   ht    = (u16*)(w + OFF_HT);
  u16*   xg    = (u16*)(w + OFF_XG);

  const size_t ht_bytes = (size_t)(Tn + 1) * Bn * Hn * 2;
  dim3 pgrid(Gn / 128, (Tn * Bn) / 128);
  const int nx4 = Tn * Bn * Hn / 4;
  const int nw4 = Gn * Hn / 4;

  // x -> bf16 into the ht region (dead until scan1), W_ih1 -> bf16 into shared Wb
  cvt_kernel<<<(nx4 + 255) / 256, 256, 0, stream>>>(x, (u16*)ht, nx4);
  cvt_kernel<<<(nw4 + 255) / 256, 256, 0, stream>>>(W_ih1, Wb, nw4);
  proj_kernel<<<pgrid, 256, 0, stream>>>((const u16*)ht, Wb, b_ih1, b_hh1, xg);
  hipMemsetAsync(ht, 0xFF, ht_bytes, stream);   // poison trail for scan1
  cvt_kernel<<<(nw4 + 255) / 256, 256, 0, stream>>>(W_ih2, Wb, nw4);  // proj1 done with Wb
  scan_kernel<<<NG * NS, 256, 0, stream>>>(xg, W_hh1, h0, c0, ht, h_mid, c_mid);
  // trail regions 1..T are exactly y1[0..T-1]
  proj_kernel<<<pgrid, 256, 0, stream>>>(ht + (size_t)Bn * Hn, Wb, b_ih2, b_hh2, xg);
  hipMemsetAsync(ht, 0xFF, ht_bytes, stream);   // re-poison for scan2
  scan_kernel<<<NG * NS, 256, 0, stream>>>(xg, W_hh2, h_mid, c_mid, ht, h2_out, c2_out);
  out_kernel<<<Bn, 128, 0, stream>>>(h2_out, W_out, b_out, out);
}

// Round 9
// 3026.209 us; speedup vs baseline: 1.8055x; 1.8055x over previous
//
#include <hip/hip_runtime.h>

typedef unsigned short u16;
typedef unsigned int u32;
typedef unsigned long long u64;
using f32x4 = __attribute__((ext_vector_type(4))) float;
using s16x8 = __attribute__((ext_vector_type(8))) short;
using u64x2 = __attribute__((ext_vector_type(2))) unsigned long long;

constexpr int Tn = 512, Bn = 64, Hn = 512, Gn = 2048, On = 128;
constexpr int NS = 16;  // gate-slice WGs per batch group
constexpr int NG = 4;   // batch groups (independent)

// -------- workspace layout (bytes) --------
constexpr size_t OFF_CMID = 0;                                    // [B][H] f32 = 128 KB
constexpr size_t OFF_HMID = OFF_CMID + (size_t)Bn * Hn * 4;       // [B][H] f32 = 128 KB
constexpr size_t OFF_XBF  = OFF_HMID + (size_t)Bn * Hn * 4;       // [T][B][H] bf16 = 32 MB
constexpr size_t OFF_HT1  = OFF_XBF + (size_t)Tn * Bn * Hn * 2;   // [T+1][B][H] bf16 = 33.6 MB
constexpr size_t OFF_HT2  = OFF_HT1 + (size_t)(Tn + 1) * Bn * Hn * 2;  // contiguous with HT1

// -------- helpers --------
__device__ __forceinline__ u16 f2b(float f) {
  union { float f; unsigned u; } v; v.f = f;
  unsigned r = v.u + 0x7fffu + ((v.u >> 16) & 1u);
  return (u16)(r >> 16);
}
__device__ __forceinline__ float b2f(u16 u) {
  union { unsigned u; float f; } v; v.u = ((unsigned)u) << 16; return v.f;
}
__device__ __forceinline__ s16x8 pack8(float4 lo, float4 hi) {
  s16x8 r;
  r[0] = (short)f2b(lo.x); r[1] = (short)f2b(lo.y); r[2] = (short)f2b(lo.z); r[3] = (short)f2b(lo.w);
  r[4] = (short)f2b(hi.x); r[5] = (short)f2b(hi.y); r[6] = (short)f2b(hi.z); r[7] = (short)f2b(hi.w);
  return r;
}
__device__ __forceinline__ float sigm(float x) {
  float e = __builtin_amdgcn_exp2f(-1.4426950408889634f * x);
  return __builtin_amdgcn_rcpf(1.0f + e);
}
__device__ __forceinline__ float tanh_(float x) {
  float e = __builtin_amdgcn_exp2f(-2.885390081777927f * x);
  return __builtin_amdgcn_rcpf(1.0f + e) * 2.0f - 1.0f;
}
// agent-scope (device-coherent, IC-visible) relaxed atomics — the proven exchange path
__device__ __forceinline__ u64 ld64_sc(const u64* p) {
  return __hip_atomic_load(p, __ATOMIC_RELAXED, __HIP_MEMORY_SCOPE_AGENT);
}
__device__ __forceinline__ void st64_sc(u64* p, u64 v) {
  __hip_atomic_store(p, v, __ATOMIC_RELAXED, __HIP_MEMORY_SCOPE_AGENT);
}

// -------- f32 -> bf16 bulk convert (x only) --------
__global__ __launch_bounds__(256)
void cvt_kernel(const float* __restrict__ in, u16* __restrict__ out, int n4) {
  const int i = blockIdx.x * 256 + threadIdx.x;
  if (i < n4) {
    float4 v = ((const float4*)in)[i];
    ushort4 o; o.x = f2b(v.x); o.y = f2b(v.y); o.z = f2b(v.z); o.w = f2b(v.w);
    ((ushort4*)out)[i] = o;
  }
}

// -------- fused persistent LSTM layer: on-the-fly input projection + scan --------
// xin: [T][B][H] bf16 (layer1: x_bf; layer2: layer1's trail regions 1..T).
// ht: [T+1][B][H] bf16 trail, pre-poisoned 0xFF. Region t = h after step t-1; region 0 = h0.
// WG (g,s): batch rows g*16..+16, gate-cols s*32..+32. Both weight slices in registers.
// Per step: xg MFMAs (from LDS x-tile, staged last step) hide under the h-poll IC hop.
__global__ __launch_bounds__(256, 1)
void scan_fused(const u16* __restrict__ xin, const float* __restrict__ Whh,
                const float* __restrict__ Wih, const float* __restrict__ bih,
                const float* __restrict__ bhh,
                const float* __restrict__ hinit, const float* __restrict__ cinit,
                u16* __restrict__ ht, float* __restrict__ h_fin, float* __restrict__ c_fin)
{
  const int g = blockIdx.x >> 4, s = blockIdx.x & (NS - 1);
  const int tid = threadIdx.x;
  const int lane = tid & 63, w = tid >> 6;
  const int x16 = lane & 15, grp = lane >> 4;
  const int jj = x16 & 7;
  const int j0 = s * 32 + w * 8;
  const int brow = g * 16;
  const int bth = brow + grp * 4;

  __shared__ char hlds[16 * 1024];       // h(t) tile, XOR-swizzled 16B chunks
  __shared__ char xlds[2 * 16 * 1024];   // x tile double buffer, same swizzle
  __shared__ u16 hstage[16][32];         // publish staging

  // loop-invariant weight fragments: W_hh AND W_ih slices (32 gate-rows x K=512 each)
  // -> 256 VGPRs; at 1 wave/SIMD the 512-VGPR budget absorbs this without spill.
  const size_t grow0 = (size_t)(0 * 2 + (x16 >> 3)) * Hn + j0 + jj;  // gate idx, tile0 (i/f)
  const size_t grow1 = (size_t)(2 + (x16 >> 3)) * Hn + j0 + jj;      // gate idx, tile1 (g/o)
  s16x8 bwh[2][16], bwi[2][16];
#pragma unroll
  for (int nt = 0; nt < 2; ++nt) {
    const size_t grow = nt ? grow1 : grow0;
#pragma unroll
    for (int ks = 0; ks < 16; ++ks) {
      const float* wp = Whh + grow * Hn + ks * 32 + grp * 8;
      float4 lo = *(const float4*)wp, hi = *(const float4*)(wp + 4);
      bwh[nt][ks] = pack8(lo, hi);
      const float* wq = Wih + grow * Hn + ks * 32 + grp * 8;
      float4 lo2 = *(const float4*)wq, hi2 = *(const float4*)(wq + 4);
      bwi[nt][ks] = pack8(lo2, hi2);
    }
  }
  const float bias0 = bih[grow0] + bhh[grow0];
  const float bias1 = bih[grow1] + bhh[grow1];

  float c[4];
#pragma unroll
  for (int r = 0; r < 4; ++r) c[r] = cinit[(size_t)(bth + r) * Hn + j0 + jj];

  // publish region 0 slice from hinit (f32 -> bf16)
  if (tid < 128) {
    const int row = tid >> 3, cq = tid & 7;
    const float* hp = hinit + (size_t)(brow + row) * Hn + s * 32 + cq * 4;
    u64 v = (u64)f2b(hp[0]) | ((u64)f2b(hp[1]) << 16)
          | ((u64)f2b(hp[2]) << 32) | ((u64)f2b(hp[3]) << 48);
    st64_sc((u64*)(ht + (size_t)(brow + row) * Hn + s * 32 + cq * 4), v);
  }

  // prologue: stage x[0] tile into xlds[0]
  {
    const int row = tid >> 6, ci = tid & 63;
#pragma unroll
    for (int i = 0; i < 4; ++i) {
      const int rr = row + 4 * i;
      u64x2 q = *(const u64x2*)(xin + (size_t)(brow + rr) * Hn + ci * 8);
      *(u64x2*)(xlds + rr * 1024 + ((ci ^ (rr & 7)) * 16)) = q;
    }
  }
  __syncthreads();

  for (int t = 0; t < Tn; ++t) {
    const u16* rt = ht + (size_t)t * Bn * Hn;
    // (a) x[t+1] tile prefetch into regs (plain loads, overlap the poll latency)
    const int tn = (t + 1 < Tn) ? t + 1 : t;
    u64x2 xr[4];
    {
      const int row = tid >> 6, ci = tid & 63;
      const u16* xsrc = xin + (size_t)tn * Bn * Hn;
#pragma unroll
      for (int i = 0; i < 4; ++i)
        xr[i] = *(const u64x2*)(xsrc + (size_t)(brow + (row + 4 * i)) * Hn + ci * 8);
    }
    // (b) issue h(t) poll loads (agent-scope; poll load IS the data load)
    const u64* p0 = (const u64*)(rt + (size_t)(brow + (tid >> 6)) * Hn) + ((tid & 63) << 1);
    u64 v[8];
#pragma unroll
    for (int i = 0; i < 4; ++i) {
      v[2 * i]     = ld64_sc(p0 + i * 512);
      v[2 * i + 1] = ld64_sc(p0 + i * 512 + 1);
    }
    // (c) xg MFMAs for step t from xlds[t&1] + register W_ih — no dependence on (a)/(b),
    // so this compute hides under the IC hop before the poll check forces the wait.
    f32x4 acc0, acc1;
    acc0[0] = bias0; acc0[1] = bias0; acc0[2] = bias0; acc0[3] = bias0;
    acc1[0] = bias1; acc1[1] = bias1; acc1[2] = bias1; acc1[3] = bias1;
    {
      const char* xb = xlds + (size_t)(t & 1) * 16384;
#pragma unroll
      for (int ks = 0; ks < 16; ++ks) {
        const s16x8 a = *(const s16x8*)(xb + x16 * 1024 + ((((ks << 2) + grp) ^ jj) * 16));
        acc0 = __builtin_amdgcn_mfma_f32_16x16x32_bf16(a, bwi[0][ks], acc0, 0, 0, 0);
        acc1 = __builtin_amdgcn_mfma_f32_16x16x32_bf16(a, bwi[1][ks], acc1, 0, 0, 0);
      }
    }
    // (d) poll check, per-chunk retry (R5 protocol)
    while (true) {
      bool all = true;
#pragma unroll
      for (int i = 0; i < 8; ++i) all = all && (v[i] != ~0ull);
      if (all) break;
      __builtin_amdgcn_s_sleep(1);
#pragma unroll
      for (int i = 0; i < 4; ++i) {
        if (v[2 * i]     == ~0ull) v[2 * i]     = ld64_sc(p0 + i * 512);
        if (v[2 * i + 1] == ~0ull) v[2 * i + 1] = ld64_sc(p0 + i * 512 + 1);
      }
    }
    // (e) stage h(t) and x[t+1] into LDS (16B-chunk XOR swizzle)
    {
      const int row = tid >> 6, ci = tid & 63;
      char* xb = xlds + (size_t)((t + 1) & 1) * 16384;
#pragma unroll
      for (int i = 0; i < 4; ++i) {
        const int rr = row + 4 * i;
        u64x2 q; q[0] = v[2 * i]; q[1] = v[2 * i + 1];
        *(u64x2*)(hlds + rr * 1024 + ((ci ^ (rr & 7)) * 16)) = q;
        *(u64x2*)(xb + rr * 1024 + ((ci ^ (rr & 7)) * 16)) = xr[i];
      }
    }
    __syncthreads();
    // (f) recurrent MFMAs from hlds + register W_hh
#pragma unroll
    for (int ks = 0; ks < 16; ++ks) {
      const s16x8 a = *(const s16x8*)(hlds + x16 * 1024 + ((((ks << 2) + grp) ^ jj) * 16));
      acc0 = __builtin_amdgcn_mfma_f32_16x16x32_bf16(a, bwh[0][ks], acc0, 0, 0, 0);
      acc1 = __builtin_amdgcn_mfma_f32_16x16x32_bf16(a, bwh[1][ks], acc1, 0, 0, 0);
    }
    // (g) gates: tile0 rows i(j)/f(j); tile1 g(j)/o(j); pair via shfl_xor(8)
    float hv[4];
#pragma unroll
    for (int r = 0; r < 4; ++r) {
      const float p0v = acc0[r], p1v = acc1[r];
      const float q0 = __shfl_xor(p0v, 8, 64);
      const float q1 = __shfl_xor(p1v, 8, 64);
      const bool lo = (x16 < 8);
      const float gi = lo ? p0v : q0;
      const float gf = lo ? q0 : p0v;
      const float gg = lo ? p1v : q1;
      const float go = lo ? q1 : p1v;
      const float cn = sigm(gf) * c[r] + sigm(gi) * tanh_(gg);
      c[r] = cn;
      hv[r] = sigm(go) * tanh_(cn);
    }
    if (x16 < 8) {
#pragma unroll
      for (int r = 0; r < 4; ++r) {
        hstage[grp * 4 + r][w * 8 + jj] = f2b(hv[r]);
        if (t == Tn - 1) {
          h_fin[(size_t)(bth + r) * Hn + j0 + jj] = hv[r];
          c_fin[(size_t)(bth + r) * Hn + j0 + jj] = c[r];
        }
      }
    }
    __syncthreads();
    // (h) publish region t+1: 128 coalesced 8B agent-scope stores (self-flagging data;
    // publishers span all 4 waves -> poll success at t+1 proves LDS/hstage reads done)
    if (!(tid & 1)) {
      const int q = tid >> 1, row = q >> 3, cq = q & 7;
      const u64 yv = *(const u64*)&hstage[row][cq * 4];
      st64_sc((u64*)(ht + (size_t)(t + 1) * Bn * Hn + (size_t)(brow + row) * Hn + s * 32 + cq * 4), yv);
    }
  }
}

// -------- output head --------
__global__ __launch_bounds__(128)
void out_kernel(const float* __restrict__ h2, const float* __restrict__ Wout,
                const float* __restrict__ bout, float* __restrict__ out)
{
  const int b = blockIdx.x, o = threadIdx.x;
  const float4* hp = (const float4*)(h2 + (size_t)b * Hn);
  const float4* wp = (const float4*)(Wout + (size_t)o * Hn);
  float acc = 0.f;
#pragma unroll 4
  for (int k = 0; k < Hn / 4; ++k) {
    float4 h4 = hp[k], w4 = wp[k];
    acc += h4.x * w4.x + h4.y * w4.y + h4.z * w4.z + h4.w * w4.w;
  }
  out[(size_t)b * On + o] = acc + bout[o];
}

extern "C" void kernel_launch(void* const* d_in, const int* in_sizes, int n_in,
                              void* d_out, int out_size, void* d_ws, size_t ws_size,
                              hipStream_t stream) {
  const float* x     = (const float*)d_in[0];
  const float* h0    = (const float*)d_in[1];
  const float* c0    = (const float*)d_in[2];
  const float* W_ih1 = (const float*)d_in[3];
  const float* W_hh1 = (const float*)d_in[4];
  const float* b_ih1 = (const float*)d_in[5];
  const float* b_hh1 = (const float*)d_in[6];
  const float* W_ih2 = (const float*)d_in[7];
  const float* W_hh2 = (const float*)d_in[8];
  const float* b_ih2 = (const float*)d_in[9];
  const float* b_hh2 = (const float*)d_in[10];
  const float* W_out = (const float*)d_in[11];
  const float* b_out = (const float*)d_in[12];

  float* out    = (float*)d_out;
  float* h2_out = out + (size_t)Bn * On;
  float* c2_out = h2_out + (size_t)Bn * Hn;

  char* w = (char*)d_ws;
  float* c_mid = (float*)(w + OFF_CMID);
  float* h_mid = (float*)(w + OFF_HMID);
  u16*   x_bf  = (u16*)(w + OFF_XBF);
  u16*   ht1   = (u16*)(w + OFF_HT1);
  u16*   ht2   = (u16*)(w + OFF_HT2);

  const size_t ht_bytes = (size_t)(Tn + 1) * Bn * Hn * 2;
  const int nx4 = Tn * Bn * Hn / 4;

  // poison both trails in one contiguous memset (0xFFFF bf16 = NaN sentinel)
  hipMemsetAsync(ht1, 0xFF, 2 * ht_bytes, stream);
  // x -> bf16
  cvt_kernel<<<(nx4 + 255) / 256, 256, 0, stream>>>(x, x_bf, nx4);
  // layer 1: fused input-projection + scan; trail ht1 (regions 1..T = y1)
  scan_fused<<<NG * NS, 256, 0, stream>>>(x_bf, W_hh1, W_ih1, b_ih1, b_hh1,
                                          h0, c0, ht1, h_mid, c_mid);
  // layer 2: x-input = layer-1 trail; quirk-faithful init from layer-1 FINAL (h,c)
  scan_fused<<<NG * NS, 256, 0, stream>>>(ht1 + (size_t)Bn * Hn, W_hh2, W_ih2, b_ih2, b_hh2,
                                          h_mid, c_mid, ht2, h2_out, c2_out);
  out_kernel<<<Bn, 128, 0, stream>>>(h2_out, W_out, b_out, out);
}